// Round 13
// baseline (346.959 us; speedup 1.0000x reference)
//
#include <hip/hip_runtime.h>
#include <hip/hip_cooperative_groups.h>
#include <math.h>

namespace cg = cooperative_groups;

#define NN 50000
#define EE 800000
#define DD 64
#define NSLOPE 0.2f
#define NBUCK 196          // bucket = dst >> 8 (256 dsts per bucket)
#define CAP 4608           // bucket capacity (mean 4082, +8 sigma)
#define CHUNK 4096         // edges per bin block
#define BINB 196           // ceil(EE/CHUNK)
#define WHB 782            // fallback wh blocks
#define NCU 256

__device__ __forceinline__ float leaky(float s) { return s > 0.f ? s : NSLOPE * s; }

// ============================ device phase bodies ============================
__device__ __forceinline__ void bin_body(
    int binBlk, int tid, const int* __restrict__ ei,
    unsigned int* __restrict__ gbuf, int* __restrict__ gCursor, char* smem) {
    int* cnt  = (int*)smem;
    int* excl = cnt + 256;
    int* cur  = cnt + 512;
    int* base = cnt + 768;
    unsigned int* pairs = (unsigned int*)(smem + 4096);
    int start = binBlk * CHUNK;
    int nedge = min(CHUNK, EE - start);
    cnt[tid] = 0; cur[tid] = 0;
    __syncthreads();
    for (int j = 0; j < CHUNK / 256; ++j) {
        int i = start + tid + j * 256;
        if (i < EE) atomicAdd(&cnt[((unsigned int)ei[EE + i]) >> 8], 1);
    }
    __syncthreads();
    int v = cnt[tid];
    excl[tid] = v; __syncthreads();
    for (int o = 1; o < 256; o <<= 1) {
        int t = (tid >= o) ? excl[tid - o] : 0;
        __syncthreads();
        excl[tid] += t;
        __syncthreads();
    }
    int ex = excl[tid] - v;
    __syncthreads();
    excl[tid] = ex;
    __syncthreads();
    for (int j = 0; j < CHUNK / 256; ++j) {
        int i = start + tid + j * 256;
        if (i < EE) {
            unsigned int src = (unsigned int)ei[i];
            unsigned int dst = (unsigned int)ei[EE + i];
            int bk = dst >> 8;
            int r = atomicAdd(&cur[bk], 1);
            pairs[excl[bk] + r] = (dst << 16) | src;
        }
    }
    if (tid < NBUCK) base[tid] = atomicAdd(&gCursor[tid], cnt[tid]);
    __syncthreads();
    for (int i = tid; i < nedge; i += 256) {
        unsigned int p = pairs[i];
        int bk = p >> 24;
        gbuf[(size_t)bk * CAP + base[bk] + (i - excl[bk])] = p;
    }
}

__device__ __forceinline__ void wh_body(
    int whBlk, int whStrideBlks, int tid,
    const float* __restrict__ x, const float* __restrict__ W,
    const float* __restrict__ bias, float* __restrict__ Wh, char* smem) {
    float4* Wl = (float4*)smem;                              // 16 KB swizzled
    float4 (*xr)[4][16] = (float4 (*)[4][16])(smem + 16384); // [wave][row][quad]
    const float4* W4 = (const float4*)W;
    const float4* x4 = (const float4*)x;
    for (int i = tid; i < 1024; i += 256) {
        int c = i >> 4, k4 = i & 15;
        Wl[c * 16 + (k4 ^ (c & 15))] = W4[i];
    }
    __syncthreads();
    int wv = tid >> 6, lane = tid & 63;
    int c = lane;
    float4 wreg[16];
#pragma unroll
    for (int k4 = 0; k4 < 16; ++k4) wreg[k4] = Wl[c * 16 + (k4 ^ (c & 15))];
    float bv = bias[c];
    int l16 = lane >> 4, q = lane & 15;
    for (int rowbase = (whBlk * 4 + wv) * 4; rowbase < NN;
         rowbase += whStrideBlks * 16) {
        xr[wv][l16][q] = x4[(size_t)(rowbase + l16) * 16 + q];
        float acc0 = bv, acc1 = bv, acc2 = bv, acc3 = bv;
#pragma unroll
        for (int k4 = 0; k4 < 16; ++k4) {
            float4 w  = wreg[k4];
            float4 q0 = xr[wv][0][k4];
            float4 q1 = xr[wv][1][k4];
            float4 q2 = xr[wv][2][k4];
            float4 q3 = xr[wv][3][k4];
            acc0 += w.x * q0.x + w.y * q0.y + w.z * q0.z + w.w * q0.w;
            acc1 += w.x * q1.x + w.y * q1.y + w.z * q1.z + w.w * q1.w;
            acc2 += w.x * q2.x + w.y * q2.y + w.z * q2.z + w.w * q2.w;
            acc3 += w.x * q3.x + w.y * q3.y + w.z * q3.z + w.w * q3.w;
        }
        Wh[(size_t)(rowbase + 0) * DD + c] = acc0;
        Wh[(size_t)(rowbase + 1) * DD + c] = acc1;
        Wh[(size_t)(rowbase + 2) * DD + c] = acc2;
        Wh[(size_t)(rowbase + 3) * DD + c] = acc3;
    }
}

__device__ __forceinline__ void csr_body(
    int k, int tid, const unsigned int* __restrict__ gbuf,
    const int* __restrict__ gCursor, int* __restrict__ off,
    unsigned short* __restrict__ csr, char* smem) {
    int* s    = (int*)smem;
    int* hist = s + 256;
    int* excl = s + 512;
    int* cur  = s + 768;
    int v = (tid < NBUCK) ? gCursor[tid] : 0;
    s[tid] = v; __syncthreads();
    for (int o = 1; o < 256; o <<= 1) {
        int t = (tid >= o) ? s[tid - o] : 0;
        __syncthreads();
        s[tid] += t;
        __syncthreads();
    }
    int base_k = (k == 0) ? 0 : s[k - 1];
    int cnt = s[k] - base_k;
    const unsigned int* bp = gbuf + (size_t)k * CAP;
    hist[tid] = 0; cur[tid] = 0;
    __syncthreads();
    for (int i = tid; i < cnt; i += 256)
        atomicAdd(&hist[(bp[i] >> 16) & 255], 1);
    __syncthreads();
    int hv = hist[tid];
    excl[tid] = hv; __syncthreads();
    for (int o = 1; o < 256; o <<= 1) {
        int t = (tid >= o) ? excl[tid - o] : 0;
        __syncthreads();
        excl[tid] += t;
        __syncthreads();
    }
    int hex = excl[tid] - hv;
    __syncthreads();
    excl[tid] = hex;
    __syncthreads();
    int dst = k * 256 + tid;
    if (dst < NN) off[dst] = base_k + hex;
    if (k == 0 && tid == 0) off[NN] = EE;
    for (int i = tid; i < cnt; i += 256) {
        unsigned int p = bp[i];
        int local = (p >> 16) & 255;
        int slot = base_k + excl[local] + atomicAdd(&cur[local], 1);
        csr[slot] = (unsigned short)(p & 0xffffu);
    }
}

__device__ __forceinline__ void fused_group(
    int g, int tid, const float4* __restrict__ Wh4, float4 av,
    const int* __restrict__ off, const unsigned short* __restrict__ csr,
    float4* __restrict__ out4) {
    int wave = tid >> 6, lane = tid & 63;
    int eb = lane >> 4, f4 = lane & 15;
    int node = g * 4 + wave;
    float4 whi = Wh4[(size_t)node * 16 + f4];
    int beg = off[node], end = off[node + 1];
    float den = 0.f;
    float4 acc = make_float4(0.f, 0.f, 0.f, 0.f);
    float4 whs_n = make_float4(0.f, 0.f, 0.f, 0.f);
    if (beg < end) {
        int i0 = beg + eb;
        int s0 = csr[(i0 < end) ? i0 : (end - 1)];
        whs_n = Wh4[(size_t)s0 * 16 + f4];
    }
    for (int base = beg; base < end; base += 4) {
        float4 whs = whs_n;
        int ni = base + 4 + eb;
        if (ni < end) {
            int s2 = csr[ni];
            whs_n = Wh4[(size_t)s2 * 16 + f4];
        }
        float t = av.x * leaky(whi.x + whs.x) + av.y * leaky(whi.y + whs.y)
                + av.z * leaky(whi.z + whs.z) + av.w * leaky(whi.w + whs.w);
        t += __shfl_xor(t, 1, 64);
        t += __shfl_xor(t, 2, 64);
        t += __shfl_xor(t, 4, 64);
        t += __shfl_xor(t, 8, 64);
        float ex = (base + eb < end) ? __expf(t) : 0.f;
        den += ex;
        acc.x += ex * whs.x; acc.y += ex * whs.y;
        acc.z += ex * whs.z; acc.w += ex * whs.w;
    }
    acc.x += __shfl_xor(acc.x, 16, 64); acc.y += __shfl_xor(acc.y, 16, 64);
    acc.z += __shfl_xor(acc.z, 16, 64); acc.w += __shfl_xor(acc.w, 16, 64);
    den   += __shfl_xor(den,   16, 64);
    acc.x += __shfl_xor(acc.x, 32, 64); acc.y += __shfl_xor(acc.y, 32, 64);
    acc.z += __shfl_xor(acc.z, 32, 64); acc.w += __shfl_xor(acc.w, 32, 64);
    den   += __shfl_xor(den,   32, 64);
    if (eb == 0) {
        float id = 1.f / fmaxf(den, 1e-9f);
        float4 o;
        o.x = 1.f / (1.f + __expf(-acc.x * id));
        o.y = 1.f / (1.f + __expf(-acc.y * id));
        o.z = 1.f / (1.f + __expf(-acc.z * id));
        o.w = 1.f / (1.f + __expf(-acc.w * id));
        out4[(size_t)node * 16 + f4] = o;
    }
}

// ============================ cooperative mega ===============================
__global__ void __launch_bounds__(256, 4) mega_kernel(
    const int* __restrict__ ei, unsigned int* __restrict__ gbuf,
    int* __restrict__ gCursor, int* __restrict__ off,
    unsigned short* __restrict__ csr,
    const float* __restrict__ x, const float* __restrict__ W,
    const float* __restrict__ bias, const float* __restrict__ a,
    float* __restrict__ Wh, float* __restrict__ out) {
    cg::grid_group grid = cg::this_grid();
    __shared__ __align__(16) char smem[20480];
    int tid = threadIdx.x;
    int G = (int)gridDim.x;

    if (blockIdx.x < BINB)
        bin_body(blockIdx.x, tid, ei, gbuf, gCursor, smem);
    else
        wh_body(blockIdx.x - BINB, G - BINB, tid, x, W, bias, Wh, smem);

    grid.sync();

    if (blockIdx.x < NBUCK)
        csr_body(blockIdx.x, tid, gbuf, gCursor, off, csr, smem);

    grid.sync();

    const float4* Wh4  = (const float4*)Wh;
    float4*       out4 = (float4*)out;
    float4 av = ((const float4*)a)[tid & 15];
    for (int g = blockIdx.x; g < NN / 4; g += G)
        fused_group(g, tid, Wh4, av, off, csr, out4);
}

// ============================ fallback kernels ===============================
__global__ void __launch_bounds__(256) bin_kernel(
    const int* __restrict__ ei, unsigned int* __restrict__ gbuf,
    int* __restrict__ gCursor) {
    __shared__ __align__(16) char smem[20480];
    bin_body(blockIdx.x, threadIdx.x, ei, gbuf, gCursor, smem);
}

__global__ void __launch_bounds__(256) csr_wh_kernel(
    const unsigned int* __restrict__ gbuf, const int* __restrict__ gCursor,
    int* __restrict__ off, unsigned short* __restrict__ csr,
    const float* __restrict__ x, const float* __restrict__ W,
    const float* __restrict__ bias, float* __restrict__ Wh) {
    __shared__ __align__(16) char smem[20480];
    if (blockIdx.x < NBUCK)
        csr_body(blockIdx.x, threadIdx.x, gbuf, gCursor, off, csr, smem);
    else
        wh_body(blockIdx.x - NBUCK, WHB, threadIdx.x, x, W, bias, Wh, smem);
}

__global__ void __launch_bounds__(256) fused_kernel(
    const float4* __restrict__ Wh4, const float4* __restrict__ a4,
    const int* __restrict__ off, const unsigned short* __restrict__ csr,
    float4* __restrict__ out4) {
    float4 av = a4[threadIdx.x & 15];
    fused_group(blockIdx.x, threadIdx.x, Wh4, av, off, csr, out4);
}

extern "C" void kernel_launch(void* const* d_in, const int* in_sizes, int n_in,
                              void* d_out, int out_size, void* d_ws, size_t ws_size,
                              hipStream_t stream) {
    const float* x = (const float*)d_in[0];
    const float* W = (const float*)d_in[1];
    const float* bias = (const float*)d_in[2];
    const float* a = (const float*)d_in[3];
    const int*   ei = (const int*)d_in[4];
    float* out = (float*)d_out;

    char* ws = (char*)d_ws;
    float*          Wh      = (float*)(ws);                    // 12,800,000 B
    int*            gCursor = (int*)(ws + 12800000);           // 1,024 B
    int*            off     = (int*)(ws + 12801024);           // 200,004 B
    unsigned int*   gbuf    = (unsigned int*)(ws + 13001216);  // 3,612,672 B
    unsigned short* csr     = (unsigned short*)(ws + 16613888);// 1,600,000 B

    hipMemsetAsync(gCursor, 0, 1024, stream);

    // self-sizing cooperative launch with validated fallback
    int nb = 0;
    hipError_t oerr = hipOccupancyMaxActiveBlocksPerMultiprocessor(
        &nb, mega_kernel, 256, 0);
    int G = (oerr == hipSuccess) ? nb * NCU : 0;
    if (G > 1024) G = 1024;
    hipError_t lerr = hipErrorUnknown;
    if (G >= BINB + 64) {
        void* args[] = {(void*)&ei, (void*)&gbuf, (void*)&gCursor, (void*)&off,
                        (void*)&csr, (void*)&x, (void*)&W, (void*)&bias,
                        (void*)&a, (void*)&Wh, (void*)&out};
        lerr = hipLaunchCooperativeKernel((const void*)mega_kernel, dim3(G),
                                          dim3(256), args, 0, stream);
    }
    if (lerr != hipSuccess) {
        bin_kernel<<<BINB, 256, 0, stream>>>(ei, gbuf, gCursor);
        csr_wh_kernel<<<NBUCK + WHB, 256, 0, stream>>>(gbuf, gCursor, off, csr,
                                                       x, W, bias, Wh);
        fused_kernel<<<NN / 4, 256, 0, stream>>>((const float4*)Wh,
                                                 (const float4*)a, off, csr,
                                                 (float4*)out);
    }
}

// Round 14
// 142.356 us; speedup vs baseline: 2.4373x; 2.4373x over previous
//
#include <hip/hip_runtime.h>
#include <hip/hip_bf16.h>
#include <math.h>

#define NN 50000
#define EE 800000
#define DD 64
#define NSLOPE 0.2f
#define NBUCK 196          // bucket = dst >> 8 (256 dsts per bucket)
#define CAP 4608           // bucket capacity (mean 4082, +8 sigma)
#define CHUNK 2048         // edges per bin block (391 blocks -> ~1.5/CU)
#define BINB ((EE + CHUNK - 1) / CHUNK)   // 391
#define WHB 782            // wh blocks; 4 waves x 4 rows each per iter

__device__ __forceinline__ float leaky(float s) { return s > 0.f ? s : NSLOPE * s; }

// ---- K1: bin edges into coarse buckets (4B packed pairs, coalesced flush) ---
__global__ void __launch_bounds__(256) bin_kernel(
    const int* __restrict__ ei, unsigned int* __restrict__ gbuf,
    int* __restrict__ gCursor) {
    __shared__ int cnt[256];
    __shared__ int excl[256];
    __shared__ int cur[256];
    __shared__ int base[256];
    __shared__ unsigned int pairs[CHUNK];
    int tid = threadIdx.x;
    int start = blockIdx.x * CHUNK;
    int nedge = min(CHUNK, EE - start);
    cnt[tid] = 0; cur[tid] = 0;
    __syncthreads();
    for (int j = 0; j < CHUNK / 256; ++j) {
        int i = start + tid + j * 256;
        if (i < EE) atomicAdd(&cnt[((unsigned int)ei[EE + i]) >> 8], 1);
    }
    __syncthreads();
    int v = cnt[tid];
    excl[tid] = v; __syncthreads();
    for (int o = 1; o < 256; o <<= 1) {
        int t = (tid >= o) ? excl[tid - o] : 0;
        __syncthreads();
        excl[tid] += t;
        __syncthreads();
    }
    int ex = excl[tid] - v;
    __syncthreads();
    excl[tid] = ex;
    __syncthreads();
    for (int j = 0; j < CHUNK / 256; ++j) {
        int i = start + tid + j * 256;
        if (i < EE) {
            unsigned int src = (unsigned int)ei[i];
            unsigned int dst = (unsigned int)ei[EE + i];
            int b = dst >> 8;
            int r = atomicAdd(&cur[b], 1);
            pairs[excl[b] + r] = (dst << 16) | src;
        }
    }
    if (tid < NBUCK) base[tid] = atomicAdd(&gCursor[tid], cnt[tid]);
    __syncthreads();
    for (int i = tid; i < nedge; i += 256) {
        unsigned int p = pairs[i];
        int b = p >> 24;
        gbuf[(size_t)b * CAP + base[b] + (i - excl[b])] = p;
    }
}

// ---- K2: blocks < NBUCK: inline bucket-scan + per-bucket CSR build
//          blocks >= NBUCK: Wh = x @ W^T + b (4-row register tile)
__global__ void __launch_bounds__(256) csr_wh_kernel(
    const unsigned int* __restrict__ gbuf, const int* __restrict__ gCursor,
    int* __restrict__ off, unsigned short* __restrict__ csr,
    const float* __restrict__ x, const float* __restrict__ W,
    const float* __restrict__ bias, float* __restrict__ Wh) {
    __shared__ __align__(16) char smem[20480];   // wh: 16KB W + 4KB xr; csr: 4KB
    int tid = threadIdx.x;

    if (blockIdx.x < NBUCK) {
        int* s    = (int*)smem;
        int* hist = s + 256;
        int* excl = s + 512;
        int* cur  = s + 768;
        int k = blockIdx.x;
        int v = (tid < NBUCK) ? gCursor[tid] : 0;
        s[tid] = v; __syncthreads();
        for (int o = 1; o < 256; o <<= 1) {
            int t = (tid >= o) ? s[tid - o] : 0;
            __syncthreads();
            s[tid] += t;
            __syncthreads();
        }
        int base_k = (k == 0) ? 0 : s[k - 1];
        int cnt = s[k] - base_k;
        const unsigned int* bp = gbuf + (size_t)k * CAP;
        hist[tid] = 0; cur[tid] = 0;
        __syncthreads();
        for (int i = tid; i < cnt; i += 256)
            atomicAdd(&hist[(bp[i] >> 16) & 255], 1);
        __syncthreads();
        int hv = hist[tid];
        excl[tid] = hv; __syncthreads();
        for (int o = 1; o < 256; o <<= 1) {
            int t = (tid >= o) ? excl[tid - o] : 0;
            __syncthreads();
            excl[tid] += t;
            __syncthreads();
        }
        int hex = excl[tid] - hv;
        __syncthreads();
        excl[tid] = hex;
        __syncthreads();
        int dst = k * 256 + tid;
        if (dst < NN) off[dst] = base_k + hex;
        if (k == 0 && tid == 0) off[NN] = EE;
        for (int i = tid; i < cnt; i += 256) {
            unsigned int p = bp[i];
            int local = (p >> 16) & 255;
            int slot = base_k + excl[local] + atomicAdd(&cur[local], 1);
            csr[slot] = (unsigned short)(p & 0xffffu);
        }
        return;
    }

    // ---------------- wh part: 4 rows per wave-iteration ----------------
    int bid = blockIdx.x - NBUCK;
    float4* Wl = (float4*)smem;                         // 16 KB, swizzled
    float4 (*xr)[4][16] = (float4 (*)[4][16])(smem + 16384);  // [wave][row][quad]
    const float4* W4 = (const float4*)W;
    const float4* x4 = (const float4*)x;
    for (int i = tid; i < 1024; i += 256) {
        int c = i >> 4, k4 = i & 15;
        Wl[c * 16 + (k4 ^ (c & 15))] = W4[i];
    }
    __syncthreads();
    int wv = tid >> 6, lane = tid & 63;
    int c = lane;
    float4 wreg[16];
#pragma unroll
    for (int k4 = 0; k4 < 16; ++k4) wreg[k4] = Wl[c * 16 + (k4 ^ (c & 15))];
    float bv = bias[c];
    int l16 = lane >> 4, q = lane & 15;                 // lane loads row l16, quad q
    for (int rowbase = (bid * 4 + wv) * 4; rowbase < NN; rowbase += WHB * 16) {
        xr[wv][l16][q] = x4[(size_t)(rowbase + l16) * 16 + q];   // 1 KB/wave coalesced
        float acc0 = bv, acc1 = bv, acc2 = bv, acc3 = bv;
#pragma unroll
        for (int k4 = 0; k4 < 16; ++k4) {
            float4 w  = wreg[k4];
            float4 q0 = xr[wv][0][k4];                  // wave-uniform broadcasts
            float4 q1 = xr[wv][1][k4];
            float4 q2 = xr[wv][2][k4];
            float4 q3 = xr[wv][3][k4];
            acc0 += w.x * q0.x + w.y * q0.y + w.z * q0.z + w.w * q0.w;
            acc1 += w.x * q1.x + w.y * q1.y + w.z * q1.z + w.w * q1.w;
            acc2 += w.x * q2.x + w.y * q2.y + w.z * q2.z + w.w * q2.w;
            acc3 += w.x * q3.x + w.y * q3.y + w.z * q3.z + w.w * q3.w;
        }
        Wh[(size_t)(rowbase + 0) * DD + c] = acc0;      // coalesced per row
        Wh[(size_t)(rowbase + 1) * DD + c] = acc1;
        Wh[(size_t)(rowbase + 2) * DD + c] = acc2;
        Wh[(size_t)(rowbase + 3) * DD + c] = acc3;
    }
}

// ---- K3: fused gather + softmax + sigmoid, 2-batch-ahead prefetch -----------
// wave/node; lane = (edge b = lane>>4, feature-quad f4 = lane&15)
__global__ void __launch_bounds__(256) fused_kernel(
    const float4* __restrict__ Wh4, const float4* __restrict__ a4,
    const int* __restrict__ off, const unsigned short* __restrict__ csr,
    float4* __restrict__ out4) {
    int wave = threadIdx.x >> 6, lane = threadIdx.x & 63;
    int node = blockIdx.x * 4 + wave;
    int b = lane >> 4, f4 = lane & 15;
    float4 av  = a4[f4];
    float4 whi = Wh4[(size_t)node * 16 + f4];
    int beg = off[node], end = off[node + 1];
    float den = 0.f;
    float4 acc = make_float4(0.f, 0.f, 0.f, 0.f);
    float4 p0 = make_float4(0.f, 0.f, 0.f, 0.f);
    float4 p1 = make_float4(0.f, 0.f, 0.f, 0.f);
    if (beg < end) {                                    // prefetch batch 0
        int i0 = beg + b;
        int s0 = csr[(i0 < end) ? i0 : (end - 1)];
        p0 = Wh4[(size_t)s0 * 16 + f4];
        int i1 = beg + 4 + b;                           // prefetch batch 1
        if (i1 < end) {
            int s1 = csr[i1];
            p1 = Wh4[(size_t)s1 * 16 + f4];
        }
    }
    for (int base = beg; base < end; base += 4) {
        float4 whs = p0;
        p0 = p1;
        int ni = base + 8 + b;                          // prefetch batch +2
        if (ni < end) {
            int s2 = csr[ni];
            p1 = Wh4[(size_t)s2 * 16 + f4];
        }
        float t = av.x * leaky(whi.x + whs.x) + av.y * leaky(whi.y + whs.y)
                + av.z * leaky(whi.z + whs.z) + av.w * leaky(whi.w + whs.w);
        t += __shfl_xor(t, 1, 64);
        t += __shfl_xor(t, 2, 64);
        t += __shfl_xor(t, 4, 64);
        t += __shfl_xor(t, 8, 64);
        float ex = (base + b < end) ? __expf(t) : 0.f;
        den += ex;
        acc.x += ex * whs.x; acc.y += ex * whs.y;
        acc.z += ex * whs.z; acc.w += ex * whs.w;
    }
    acc.x += __shfl_xor(acc.x, 16, 64); acc.y += __shfl_xor(acc.y, 16, 64);
    acc.z += __shfl_xor(acc.z, 16, 64); acc.w += __shfl_xor(acc.w, 16, 64);
    den   += __shfl_xor(den,   16, 64);
    acc.x += __shfl_xor(acc.x, 32, 64); acc.y += __shfl_xor(acc.y, 32, 64);
    acc.z += __shfl_xor(acc.z, 32, 64); acc.w += __shfl_xor(acc.w, 32, 64);
    den   += __shfl_xor(den,   32, 64);
    if (b == 0) {
        float id = 1.f / fmaxf(den, 1e-9f);
        float4 o;
        o.x = 1.f / (1.f + __expf(-acc.x * id));
        o.y = 1.f / (1.f + __expf(-acc.y * id));
        o.z = 1.f / (1.f + __expf(-acc.z * id));
        o.w = 1.f / (1.f + __expf(-acc.w * id));
        out4[(size_t)node * 16 + f4] = o;
    }
}

extern "C" void kernel_launch(void* const* d_in, const int* in_sizes, int n_in,
                              void* d_out, int out_size, void* d_ws, size_t ws_size,
                              hipStream_t stream) {
    const float* x = (const float*)d_in[0];
    const float* W = (const float*)d_in[1];
    const float* b = (const float*)d_in[2];
    const float* a = (const float*)d_in[3];
    const int*   ei = (const int*)d_in[4];
    float* out = (float*)d_out;

    char* ws = (char*)d_ws;
    float*          Wh      = (float*)(ws);                    // 12,800,000 B
    int*            gCursor = (int*)(ws + 12800000);           // 1,024 B
    int*            off     = (int*)(ws + 12801024);           // 200,004 B
    unsigned int*   gbuf    = (unsigned int*)(ws + 13001216);  // 3,612,672 B
    unsigned short* csr     = (unsigned short*)(ws + 16613888);// 1,600,000 B

    hipMemsetAsync(gCursor, 0, 1024, stream);
    bin_kernel<<<BINB, 256, 0, stream>>>(ei, gbuf, gCursor);
    csr_wh_kernel<<<NBUCK + WHB, 256, 0, stream>>>(gbuf, gCursor, off, csr,
                                                   x, W, b, Wh);
    fused_kernel<<<NN / 4, 256, 0, stream>>>((const float4*)Wh, (const float4*)a,
                                             off, csr, (float4*)out);
}